// Round 1
// baseline (51.742 us; speedup 1.0000x reference)
//
#include <hip/hip_runtime.h>

#define BATCH 1024
#define N_OUT 4096

// h[k,b]: k==0 -> 0, k==1 -> 1, even k>=2 -> x[(k-2)/2, b], odd k>=3 -> 1 - x[(k-3)/2, b]
__device__ __forceinline__ float Hval(int k, const float* __restrict__ x, int b) {
    if (k < 2) return (float)k;           // wave-uniform branch (k is same across block)
    float v = x[((k - 2) >> 1) * BATCH + b];
    return (k & 1) ? 1.0f - v : v;
}

__global__ __launch_bounds__(256) void knowledge_fused_kernel(
    const float* __restrict__ x,
    const int2* __restrict__ idx0,
    const int2* __restrict__ idx1,
    const int2* __restrict__ idx2,
    const int2* __restrict__ idx3,
    float* __restrict__ out)
{
    const int i = blockIdx.x;                              // output row, 0..4095
    const int b = blockIdx.y * blockDim.x + threadIdx.x;   // batch column, 0..1023

    const int2 p3 = idx3[i];
    float acc3 = 0.0f;
    #pragma unroll
    for (int t = 0; t < 2; ++t) {
        const int j2 = (t == 0) ? p3.x : p3.y;
        const int2 p2 = idx2[j2];
        float prod2 = 1.0f;
        #pragma unroll
        for (int u = 0; u < 2; ++u) {
            const int j1 = (u == 0) ? p2.x : p2.y;
            const int2 p1 = idx1[j1];
            float sum1 = 0.0f;
            #pragma unroll
            for (int v = 0; v < 2; ++v) {
                const int j0 = (v == 0) ? p1.x : p1.y;
                const int2 p0 = idx0[j0];
                const float a = Hval(p0.x, x, b);
                const float c = Hval(p0.y, x, b);
                sum1 += a * c;             // ProductLayer leaf then SumLayer
            }
            prod2 *= sum1;                 // ProductLayer (layer 2)
        }
        acc3 += prod2;                     // SumLayer (layer 3)
    }
    out[(size_t)i * BATCH + b] = acc3;
}

extern "C" void kernel_launch(void* const* d_in, const int* in_sizes, int n_in,
                              void* d_out, int out_size, void* d_ws, size_t ws_size,
                              hipStream_t stream) {
    const float* x    = (const float*)d_in[0];
    const int2*  idx0 = (const int2*)d_in[1];
    const int2*  idx1 = (const int2*)d_in[2];
    const int2*  idx2 = (const int2*)d_in[3];
    const int2*  idx3 = (const int2*)d_in[4];
    float* out = (float*)d_out;

    dim3 grid(N_OUT, BATCH / 256);
    dim3 block(256);
    knowledge_fused_kernel<<<grid, block, 0, stream>>>(x, idx0, idx1, idx2, idx3, out);
}

// Round 2
// 32.155 us; speedup vs baseline: 1.6091x; 1.6091x over previous
//
#include <hip/hip_runtime.h>
#include <hip/hip_fp16.h>

#define BATCH  1024
#define NVARS  2048
#define N_OUT  4096
#define SC     16                 // batch columns per slice
#define NSLICE (BATCH / SC)       // 64
#define CHUNK  512                // outputs per block
#define NCHUNK (N_OUT / CHUNK)    // 8
#define NLEAF  16

__device__ __forceinline__ __half2 u2h2(unsigned u) {
    union { unsigned u; __half2 h; } c; c.u = u; return c.h;
}
__device__ __forceinline__ unsigned h22u(__half2 h) {
    union { unsigned u; __half2 h; } c; c.h = h; return c.u;
}

// ---------------- flatten: build per-output leaf table ----------------
// T[i*16 + n] = int2{ rowword = row*8, scbits = half2(s, c) }  so leaf = s*x[row]+c
__global__ void flatten_kernel(const int2* __restrict__ idx0,
                               const int2* __restrict__ idx1,
                               const int2* __restrict__ idx2,
                               const int2* __restrict__ idx3,
                               int2* __restrict__ T)
{
    int i = blockIdx.x * blockDim.x + threadIdx.x;
    if (i >= N_OUT) return;
    int2 p3 = idx3[i];
    int n = 0;
    #pragma unroll
    for (int t = 0; t < 2; ++t) {
        int2 p2 = idx2[t ? p3.y : p3.x];
        #pragma unroll
        for (int u = 0; u < 2; ++u) {
            int2 p1 = idx1[u ? p2.y : p2.x];
            #pragma unroll
            for (int v = 0; v < 2; ++v) {
                int2 p0 = idx0[v ? p1.y : p1.x];
                #pragma unroll
                for (int e = 0; e < 2; ++e) {
                    int k = e ? p0.y : p0.x;
                    int rowword; float s, c;
                    if (k < 2) { rowword = 0; s = 0.0f; c = (float)k; }
                    else {
                        rowword = ((k - 2) >> 1) * 8;
                        if (k & 1) { s = -1.0f; c = 1.0f; }
                        else       { s =  1.0f; c = 0.0f; }
                    }
                    __half2 sc = __halves2half2(__float2half(s), __float2half(c));
                    int2 ent; ent.x = rowword; ent.y = (int)h22u(sc);
                    T[(size_t)i * NLEAF + n] = ent;
                    ++n;
                }
            }
        }
    }
}

// ---------------- main: LDS-staged fused evaluation ----------------
__global__ __launch_bounds__(256) void knowledge_main(
    const float* __restrict__ x,
    const int2* __restrict__ T,
    float* __restrict__ out)
{
    __shared__ unsigned xs[NVARS * 8];   // 64 KB: word w of row r = half2 cols {2w, 2w+1}

    const int bx  = blockIdx.x;
    const int s   = bx & (NSLICE - 1);   // slice index
    const int ch  = bx >> 6;             // output chunk
    const int c0  = s * SC;
    const int tid = threadIdx.x;

    // ---- stage x slice (2048 rows x 16 cols) as fp16 ----
    const float4* x4 = (const float4*)x;
    #pragma unroll 4
    for (int it = 0; it < 32; ++it) {
        int f = it * 256 + tid;          // [0, 8192)
        int r = f >> 2, q = f & 3;
        float4 vv = x4[(size_t)r * (BATCH / 4) + (c0 >> 2) + q];
        __half2 h0 = __floats2half2_rn(vv.x, vv.y);
        __half2 h1 = __floats2half2_rn(vv.z, vv.w);
        xs[r * 8 + q * 2    ] = h22u(h0);
        xs[r * 8 + q * 2 + 1] = h22u(h1);
    }
    __syncthreads();

    const int w  = tid >> 6;        // wave 0..3
    const int g  = (tid >> 3) & 7;  // group-in-wave 0..7 (one output each)
    const int lp = tid & 7;         // word (col-pair) 0..7

    for (int p = 0; p < 16; ++p) {
        const int i = ch * CHUNK + p * 32 + w * 8 + g;
        const int4* Tp = (const int4*)(T + (size_t)i * NLEAF);

        float pp0[8], pp1[8];        // pair products for col 2lp, 2lp+1
        #pragma unroll
        for (int j = 0; j < 8; ++j) {
            int4 tt = Tp[j];         // leaves 2j (x,y) and 2j+1 (z,w)
            unsigned wa = xs[tt.x + lp];
            unsigned wb = xs[tt.z + lp];
            __half2 scA = u2h2((unsigned)tt.y);
            __half2 scB = u2h2((unsigned)tt.w);
            __half2 sA = __half2half2(__low2half(scA));
            __half2 cA = __half2half2(__high2half(scA));
            __half2 sB = __half2half2(__low2half(scB));
            __half2 cB = __half2half2(__high2half(scB));
            __half2 ra = __hfma2(u2h2(wa), sA, cA);
            __half2 rb = __hfma2(u2h2(wb), sB, cB);
            __half2 pr = __hmul2(ra, rb);
            float2 pf = __half22float2(pr);
            pp0[j] = pf.x; pp1[j] = pf.y;
        }
        // tree: out = (pp0+pp1)*(pp2+pp3) + (pp4+pp5)*(pp6+pp7)
        float o0 = (pp0[0] + pp0[1]) * (pp0[2] + pp0[3])
                 + (pp0[4] + pp0[5]) * (pp0[6] + pp0[7]);
        float o1 = (pp1[0] + pp1[1]) * (pp1[2] + pp1[3])
                 + (pp1[4] + pp1[5]) * (pp1[6] + pp1[7]);

        *reinterpret_cast<float2*>(out + (size_t)i * BATCH + c0 + 2 * lp) =
            make_float2(o0, o1);
    }
}

// ---------------- fallback (round-1 kernel) if ws too small ----------------
__device__ __forceinline__ float Hval(int k, const float* __restrict__ x, int b) {
    if (k < 2) return (float)k;
    float v = x[((k - 2) >> 1) * BATCH + b];
    return (k & 1) ? 1.0f - v : v;
}

__global__ __launch_bounds__(256) void knowledge_fused_kernel(
    const float* __restrict__ x,
    const int2* __restrict__ idx0,
    const int2* __restrict__ idx1,
    const int2* __restrict__ idx2,
    const int2* __restrict__ idx3,
    float* __restrict__ out)
{
    const int i = blockIdx.x;
    const int b = blockIdx.y * blockDim.x + threadIdx.x;
    const int2 p3 = idx3[i];
    float acc3 = 0.0f;
    #pragma unroll
    for (int t = 0; t < 2; ++t) {
        const int2 p2 = idx2[t ? p3.y : p3.x];
        float prod2 = 1.0f;
        #pragma unroll
        for (int u = 0; u < 2; ++u) {
            const int2 p1 = idx1[u ? p2.y : p2.x];
            float sum1 = 0.0f;
            #pragma unroll
            for (int v = 0; v < 2; ++v) {
                const int2 p0 = idx0[v ? p1.y : p1.x];
                sum1 += Hval(p0.x, x, b) * Hval(p0.y, x, b);
            }
            prod2 *= sum1;
        }
        acc3 += prod2;
    }
    out[(size_t)i * BATCH + b] = acc3;
}

extern "C" void kernel_launch(void* const* d_in, const int* in_sizes, int n_in,
                              void* d_out, int out_size, void* d_ws, size_t ws_size,
                              hipStream_t stream) {
    const float* x    = (const float*)d_in[0];
    const int2*  idx0 = (const int2*)d_in[1];
    const int2*  idx1 = (const int2*)d_in[2];
    const int2*  idx2 = (const int2*)d_in[3];
    const int2*  idx3 = (const int2*)d_in[4];
    float* out = (float*)d_out;

    const size_t t_bytes = (size_t)N_OUT * NLEAF * sizeof(int2);  // 512 KB
    if (ws_size >= t_bytes) {
        int2* T = (int2*)d_ws;
        flatten_kernel<<<(N_OUT + 255) / 256, 256, 0, stream>>>(idx0, idx1, idx2, idx3, T);
        knowledge_main<<<NSLICE * NCHUNK, 256, 0, stream>>>(x, T, out);
    } else {
        dim3 grid(N_OUT, BATCH / 256);
        knowledge_fused_kernel<<<grid, 256, 0, stream>>>(x, idx0, idx1, idx2, idx3, out);
    }
}